// Round 5
// baseline (427.915 us; speedup 1.0000x reference)
//
#include <hip/hip_runtime.h>
#include <math.h>

// Gating: logits = x @ W^T + b (D=1024, E=16); softmax; top-2 scatter.
// Outputs concatenated in d_out: gated^T [16,65536], weights^T [16,65536].
//
// R5: coalesced LDS staging + expert-split waves.
//  - R4's residual cost was the per-lane row-gather of x: 64 distinct 128B
//    lines per load instruction (8x the TA work of coalesced). Here x is
//    staged through a double-buffered LDS tile with fully coalesced loads
//    (256B segments, 8 lines/instr).
//  - Waves split EXPERTS (4 each over full D), not D: acc is 4 VGPRs, no
//    cross-wave dot reduction. W stays wave-uniform -> s_load (SMEM pipe).
//  - One barrier per chunk; 4 independent blocks/CU (LDS-capped) provide
//    TLP so barriers don't lockstep the CU.
// Floors: HBM 264MB -> ~42us; VALU 16.8M fma -> 13.7us. Memory-bound target.

constexpr int D    = 1024;
constexpr int D4   = D / 4;          // 256 float4 per token row
constexpr int NE   = 16;
constexpr int NTOK = 8 * 8192;       // 65536 tokens
constexpr int TPB  = 256;            // 4 waves
constexpr int TOKS = 64;             // tokens per block
constexpr int CH4  = 16;             // float4 per token per chunk (64 dims)
constexpr int NCH  = D4 / CH4;       // 16 chunks
constexpr int TSTR = CH4 + 1;        // 17 float4: pad breaks pow2 bank stride
constexpr int EPW  = NE / 4;         // 4 experts per wave
constexpr int LSTR = NE + 4;         // logit-exchange row stride (floats)

__global__ __launch_bounds__(TPB, 4) void gating_kernel(
    const float* __restrict__ x,
    const float* __restrict__ W,
    const float* __restrict__ bias,
    float* __restrict__ out)
{
    __shared__ float4 tile[2][TOKS * TSTR];   // 2 x 17408 B = 34816 B
    const int tid  = threadIdx.x;
    const int lane = tid & 63;                // token within block (compute)
    const int wv   = tid >> 6;                // wave -> expert group
    const long blockTok = (long)blockIdx.x * TOKS;

    // staging mapping: idx = s*256 + tid -> token = s*16 + (tid>>4), col = tid&15
    const int srow = tid >> 4;                // 0..15
    const int scol = tid & 15;                // 0..15
    const float4* __restrict__ xg = (const float4*)x + blockTok * D4;

    // wave-uniform W base -> scalar loads with immediate offsets
    const float4* __restrict__ Wq =
        (const float4*)W + (size_t)__builtin_amdgcn_readfirstlane(wv * EPW * D4);

    // prefetch chunk 0 (coalesced: 16 lanes = 256B segment per token)
    float4 pf[4];
    #pragma unroll
    for (int s = 0; s < 4; ++s)
        pf[s] = xg[(s * 16 + srow) * D4 + scol];

    float acc[EPW];
    #pragma unroll
    for (int i = 0; i < EPW; ++i) acc[i] = 0.0f;

    #pragma unroll 1
    for (int c = 0; c < NCH; ++c) {
        // spill prefetched chunk into tile[c&1]
        #pragma unroll
        for (int s = 0; s < 4; ++s)
            tile[c & 1][(s * 16 + srow) * TSTR + scol] = pf[s];
        __syncthreads();
        // issue next chunk's coalesced loads (consumed next iteration)
        if (c + 1 < NCH) {
            #pragma unroll
            for (int s = 0; s < 4; ++s)
                pf[s] = xg[(s * 16 + srow) * D4 + (c + 1) * CH4 + scol];
        }
        // compute: lane's token row vs this wave's 4 experts (W via SMEM)
        const float4* __restrict__ row = &tile[c & 1][lane * TSTR];
        #pragma unroll
        for (int j = 0; j < CH4; ++j) {
            const float4 xv = row[j];
            #pragma unroll
            for (int i = 0; i < EPW; ++i) {
                const float4 w4 = Wq[i * D4 + c * CH4 + j];
                acc[i] = fmaf(xv.x, w4.x, acc[i]);
                acc[i] = fmaf(xv.y, w4.y, acc[i]);
                acc[i] = fmaf(xv.z, w4.z, acc[i]);
                acc[i] = fmaf(xv.w, w4.w, acc[i]);
            }
        }
        // NOTE: iter c+2's overwrite of tile[c&1] is ordered after every
        // wave's compute(c) by iter c+1's __syncthreads() -> 1 barrier/chunk.
    }

    // ---- exchange 4-expert logits across waves via LDS ----
    float* lbuf = (float*)&tile[0][0];   // reuse buf0 (last compute used buf1)
    #pragma unroll
    for (int i = 0; i < EPW; ++i)
        lbuf[lane * LSTR + wv * EPW + i] = acc[i];
    __syncthreads();

    // all 4 waves redundantly compute the epilogue for token `lane`
    float logits[NE];
    float m = -INFINITY;
    #pragma unroll
    for (int e = 0; e < NE; ++e) {
        logits[e] = lbuf[lane * LSTR + e] + bias[e];
        m = fmaxf(m, logits[e]);
    }
    float w[NE];
    float s = 0.0f;
    #pragma unroll
    for (int e = 0; e < NE; ++e) {
        w[e] = __expf(logits[e] - m);
        s += w[e];
    }
    const float inv = 1.0f / s;
    #pragma unroll
    for (int e = 0; e < NE; ++e) w[e] *= inv;

    // top-2 (ties -> lowest index, matching lax.top_k); validated R1-R4
    float b1 = -1.0f; int i1 = 0;
    float b2 = -1.0f; int i2 = 0;
    #pragma unroll
    for (int e = 0; e < NE; ++e) {
        if (w[e] > b1)      { b2 = b1; i2 = i1; b1 = w[e]; i1 = e; }
        else if (w[e] > b2) { b2 = w[e]; i2 = e; }
    }

    // wave wv stores its 4-expert slice for both outputs (coalesced per e)
    float* __restrict__ out0 = out;                    // gated^T  [16][65536]
    float* __restrict__ out1 = out + (long)NE * NTOK;  // weights^T[16][65536]
    #pragma unroll
    for (int i = 0; i < EPW; ++i) {
        const int e = wv * EPW + i;
        const float g = (e == i1) ? b1 : ((e == i2) ? b2 : 0.0f);
        out0[(long)e * NTOK + blockTok + lane] = g;
        out1[(long)e * NTOK + blockTok + lane] = w[e];
    }
}

extern "C" void kernel_launch(void* const* d_in, const int* in_sizes, int n_in,
                              void* d_out, int out_size, void* d_ws, size_t ws_size,
                              hipStream_t stream) {
    const float* x = (const float*)d_in[0];
    const float* W = (const float*)d_in[1];
    const float* b = (const float*)d_in[2];
    float* out = (float*)d_out;

    dim3 grid(NTOK / TOKS);   // 1024 blocks; 4 blocks/CU (LDS-capped)
    dim3 block(TPB);
    gating_kernel<<<grid, block, 0, stream>>>(x, W, b, out);
}

// Round 6
// 381.328 us; speedup vs baseline: 1.1222x; 1.1222x over previous
//
#include <hip/hip_runtime.h>
#include <math.h>

// Gating: logits = x @ W^T + b (D=1024, E=16); softmax; top-2 scatter.
// Outputs concatenated in d_out: gated^T [16,65536], weights^T [16,65536].
//
// R6: bf16x6 emulated-fp32 MFMA. R3/R4/R5 all plateaued at 140-200us on the
// same structural wall: ~16K W-fetch instructions per CU (any pipe), because
// per-lane fp32 paths have no operand reuse. MFMA's B-fragment feeds 16
// tokens per 16B/lane -> W-fetch instr count drops ~30x. Precision: top-2
// selection needs fp32-exact logits (a rank-2/3 flip = ~0.2 absmax), so x,W
// are split into 3 bf16 planes (exact RNE bit-split) and 6 MFMA products
// >= 2^-16 weight are accumulated in the fp32 MFMA accumulator -> logit
// error ~1e-7 ~= fp32. W planes pre-split into d_ws by a prep kernel
// (re-run every launch; ws is re-poisoned by the harness).
// Budget/CU: MFMA 15K cyc, LDS ~37K, split ~29K cyc; HBM 42us floor.

typedef __attribute__((ext_vector_type(8))) short frag8;   // 8 bf16 = 4 VGPR
typedef __attribute__((ext_vector_type(4))) float f32x4;
typedef unsigned short u16;
typedef unsigned int u32;

constexpr int D    = 1024;
constexpr int D4   = 256;          // float4 per token row
constexpr int NE   = 16;
constexpr int NTOK = 65536;
constexpr int TPB  = 256;          // 4 waves
constexpr int TOKS = 64;           // tokens per block
constexpr int NCH  = 16;           // 64-dim K-chunks
constexpr int RS   = 72;           // LDS row stride (bf16): 64 data + 8 pad
constexpr int PL   = TOKS * RS;    // u16 per plane
constexpr int LSTR = 20;           // logit-exchange row stride (floats)

__device__ __forceinline__ u16 bf_rne(float v, float* back) {
    u32 u = __float_as_uint(v);
    u32 r = (u + 0x7FFFu + ((u >> 16) & 1u)) >> 16;   // RNE to bf16
    *back = __uint_as_float(r << 16);
    return (u16)r;
}

__device__ __forceinline__ void split3(float v, u16& a, u16& b, u16& c) {
    float t;
    a = bf_rne(v, &t); float r = v - t;   // exact residual
    b = bf_rne(r, &t); r -= t;            // exact residual
    c = bf_rne(r, &t);
}

__device__ __forceinline__ void loadX(const float4* __restrict__ xg4, int c,
                                      int tid, float4* pf) {
    const int col = tid & 15;
    #pragma unroll
    for (int s = 0; s < 4; ++s) {                       // coalesced 256B/row
        const int r = (s << 4) + (tid >> 4);
        pf[s] = xg4[r * D4 + c * 16 + col];
    }
}

__device__ __forceinline__ void loadB(const u16* __restrict__ wb, int c,
                                      frag8 Bf[2][3]) {
    #pragma unroll
    for (int ks = 0; ks < 2; ++ks)
        #pragma unroll
        for (int p = 0; p < 3; ++p)                     // B[n=l&15][k] 16B rows
            Bf[ks][p] = *(const frag8*)(wb + p * (NE * D) + (c * 2 + ks) * 32);
}

__device__ __forceinline__ void stage(const float4* pf, u16* __restrict__ lbuf,
                                      int tid) {
    const int col = tid & 15;
    #pragma unroll
    for (int s = 0; s < 4; ++s) {
        const int r = (s << 4) + (tid >> 4);
        u16 h[3][4];
        split3(pf[s].x, h[0][0], h[1][0], h[2][0]);
        split3(pf[s].y, h[0][1], h[1][1], h[2][1]);
        split3(pf[s].z, h[0][2], h[1][2], h[2][2]);
        split3(pf[s].w, h[0][3], h[1][3], h[2][3]);
        #pragma unroll
        for (int p = 0; p < 3; ++p) {
            u32 lo = (u32)h[p][0] | ((u32)h[p][1] << 16);
            u32 hi = (u32)h[p][2] | ((u32)h[p][3] << 16);
            *(uint2*)&lbuf[p * PL + r * RS + (col << 2)] = make_uint2(lo, hi);
        }
    }
}

__device__ __forceinline__ void compute(const u16* __restrict__ lbuf,
                                        const frag8 Bf[2][3],
                                        int l, int w, f32x4& acc) {
    const u16* arow = lbuf + (w * 16 + (l & 15)) * RS + (l >> 4) * 8;
    #pragma unroll
    for (int ks = 0; ks < 2; ++ks) {
        frag8 a1 = *(const frag8*)(arow + 0 * PL + ks * 32);
        frag8 a2 = *(const frag8*)(arow + 1 * PL + ks * 32);
        frag8 a3 = *(const frag8*)(arow + 2 * PL + ks * 32);
        // 6 products >= 2^-16 weight, small terms first
        acc = __builtin_amdgcn_mfma_f32_16x16x32_bf16(a3, Bf[ks][0], acc, 0, 0, 0);
        acc = __builtin_amdgcn_mfma_f32_16x16x32_bf16(a2, Bf[ks][1], acc, 0, 0, 0);
        acc = __builtin_amdgcn_mfma_f32_16x16x32_bf16(a1, Bf[ks][2], acc, 0, 0, 0);
        acc = __builtin_amdgcn_mfma_f32_16x16x32_bf16(a2, Bf[ks][0], acc, 0, 0, 0);
        acc = __builtin_amdgcn_mfma_f32_16x16x32_bf16(a1, Bf[ks][1], acc, 0, 0, 0);
        acc = __builtin_amdgcn_mfma_f32_16x16x32_bf16(a1, Bf[ks][0], acc, 0, 0, 0);
    }
}

__global__ void prep_w(const float* __restrict__ W, u16* __restrict__ wsp) {
    const int i = blockIdx.x * 256 + threadIdx.x;
    if (i < NE * D) {
        u16 a, b, c;
        split3(W[i], a, b, c);
        wsp[i] = a; wsp[NE * D + i] = b; wsp[2 * NE * D + i] = c;
    }
}

__global__ __launch_bounds__(TPB, 2) void gating_mfma(
    const float* __restrict__ x,
    const float* __restrict__ bias,
    const u16* __restrict__ wsp,
    float* __restrict__ out)
{
    __shared__ __align__(16) u16 xls[2 * 3 * PL];   // 55296 B -> 2 blocks/CU
    const int tid = threadIdx.x;
    const int l = tid & 63, w = tid >> 6;
    const long blockTok = (long)blockIdx.x * TOKS;
    const float4* __restrict__ xg4 = (const float4*)x + blockTok * D4;
    const u16* __restrict__ wb = wsp + (l & 15) * D + (l >> 4) * 8;

    float4 pfA[4], pfB[4];
    frag8 BfA[2][3], BfB[2][3];
    loadX(xg4, 0, tid, pfA);
    loadB(wb, 0, BfA);
    f32x4 acc = {0.f, 0.f, 0.f, 0.f};

    // One barrier per chunk; buf overwrite at c+2 is ordered after every
    // wave's compute(c) by the barrier at c+1 (R5-proven ordering).
    #pragma unroll 1
    for (int c = 0; c < NCH; c += 2) {
        stage(pfA, xls, tid);
        __syncthreads();
        loadX(xg4, c + 1, tid, pfB);
        loadB(wb, c + 1, BfB);
        compute(xls, BfA, l, w, acc);

        stage(pfB, xls + 3 * PL, tid);
        __syncthreads();
        if (c + 2 < NCH) { loadX(xg4, c + 2, tid, pfA); loadB(wb, c + 2, BfA); }
        compute(xls + 3 * PL, BfB, l, w, acc);
    }

    // ---- epilogue: C/D layout col=lane&15 (expert), row=quad*4+reg (token) ----
    float* lb = (float*)xls;   // buf0 region; last compute used buf1 -> safe
    #pragma unroll
    for (int r = 0; r < 4; ++r)
        lb[(w * 16 + (l >> 4) * 4 + r) * LSTR + (l & 15)] = acc[r];
    __syncthreads();

    float logits[NE];
    float mx = -INFINITY;
    #pragma unroll
    for (int e = 0; e < NE; ++e) {
        logits[e] = lb[l * LSTR + e] + bias[e];
        mx = fmaxf(mx, logits[e]);
    }
    float wt[NE];
    float s = 0.0f;
    #pragma unroll
    for (int e = 0; e < NE; ++e) { wt[e] = __expf(logits[e] - mx); s += wt[e]; }
    const float inv = 1.0f / s;
    #pragma unroll
    for (int e = 0; e < NE; ++e) wt[e] *= inv;

    // top-2 (ties -> lowest index, matching lax.top_k); validated R1-R5
    float b1 = -1.0f; int i1 = 0;
    float b2 = -1.0f; int i2 = 0;
    #pragma unroll
    for (int e = 0; e < NE; ++e) {
        if (wt[e] > b1)      { b2 = b1; i2 = i1; b1 = wt[e]; i1 = e; }
        else if (wt[e] > b2) { b2 = wt[e]; i2 = e; }
    }

    float* __restrict__ out0 = out;                    // gated^T  [16][65536]
    float* __restrict__ out1 = out + (long)NE * NTOK;  // weights^T[16][65536]
    #pragma unroll
    for (int i = 0; i < 4; ++i) {                      // wave's 4-expert slice
        const int e = w * 4 + i;
        const float g = (e == i1) ? b1 : ((e == i2) ? b2 : 0.0f);
        out0[(long)e * NTOK + blockTok + l] = g;
        out1[(long)e * NTOK + blockTok + l] = wt[e];
    }
}

extern "C" void kernel_launch(void* const* d_in, const int* in_sizes, int n_in,
                              void* d_out, int out_size, void* d_ws, size_t ws_size,
                              hipStream_t stream) {
    const float* x = (const float*)d_in[0];
    const float* W = (const float*)d_in[1];
    const float* b = (const float*)d_in[2];
    float* out = (float*)d_out;
    u16* wsp = (u16*)d_ws;                 // 3 planes x 16384 bf16 = 96 KB

    prep_w<<<64, 256, 0, stream>>>(W, wsp);
    gating_mfma<<<NTOK / TOKS, TPB, 0, stream>>>(x, b, wsp, out);
}

// Round 7
// 375.518 us; speedup vs baseline: 1.1395x; 1.0155x over previous
//
#include <hip/hip_runtime.h>
#include <math.h>

// Gating: logits = x @ W^T + b (D=1024, E=16); softmax; top-2 scatter.
// Outputs concatenated in d_out: gated^T [16,65536], weights^T [16,65536].
//
// R7: R6's bf16x6 MFMA numerics (validated) with the pipeline rebuilt:
//  - x staged as RAW fp32 via global_load_lds width=16 (no VGPR round trip,
//    no staging VALU). XOR block-swizzle (cb ^= row&15) on the staging
//    SOURCE address compensates for the no-padding rule; reads XOR the same
//    key -> 2-way-max bank aliasing (free, m136).
//  - split3 moved to consumption: ds_read fp32 -> in-register split -> MFMA,
//    overlapping the HBM stream instead of gating the barrier.
//  - 32 KB LDS + <=128 VGPR -> 4 blocks/CU (16 waves/CU), m97 barrier
//    placement (issue c+1 after barrier(c), drain at barrier(c+1)).
// Floors: HBM ~41us; split VALU ~19us; MFMA ~1.6us -> memory-bound target.

typedef __attribute__((ext_vector_type(8))) short frag8;   // 8 bf16 = 4 VGPR
typedef __attribute__((ext_vector_type(4))) float f32x4;
typedef unsigned short u16;
typedef unsigned int u32;

constexpr int D    = 1024;
constexpr int NE   = 16;
constexpr int NTOK = 65536;
constexpr int TPB  = 256;          // 4 waves
constexpr int TOKS = 64;           // tokens per block
constexpr int NCH  = 16;           // 64-dim K-chunks
constexpr int BUFF = 4096;         // floats per chunk buffer (64 tok x 64 d)
constexpr int LSTR = 20;           // logit-exchange row stride (floats)

__device__ __forceinline__ u16 bf_rne(float v, float* back) {
    u32 u = __float_as_uint(v);
    u32 r = (u + 0x7FFFu + ((u >> 16) & 1u)) >> 16;   // RNE to bf16
    *back = __uint_as_float(r << 16);
    return (u16)r;
}

__device__ __forceinline__ void split3(float v, u16& a, u16& b, u16& c) {
    float t;
    a = bf_rne(v, &t); float r = v - t;   // exact residual (Sterbenz)
    b = bf_rne(r, &t); r -= t;
    c = bf_rne(r, &t);
}

// split a pair of fp32 into 3 packed bf16x2 dwords (planes 1..3)
__device__ __forceinline__ void split2pk(float lo, float hi,
                                         u32& p1, u32& p2, u32& p3) {
    u16 a0, b0, c0, a1, b1, c1;
    split3(lo, a0, b0, c0);
    split3(hi, a1, b1, c1);
    p1 = (u32)a0 | ((u32)a1 << 16);
    p2 = (u32)b0 | ((u32)b1 << 16);
    p3 = (u32)c0 | ((u32)c1 << 16);
}

__device__ __forceinline__ void async16(const float* g, float* l) {
    __builtin_amdgcn_global_load_lds(
        (const __attribute__((address_space(1))) void*)g,
        (__attribute__((address_space(3))) void*)l, 16, 0, 0);
}

__device__ __forceinline__ void loadB(const u16* __restrict__ wb, int c,
                                      frag8 Bf[2][3]) {
    #pragma unroll
    for (int ks = 0; ks < 2; ++ks)
        #pragma unroll
        for (int p = 0; p < 3; ++p)     // B[n=l&15][k=(l>>4)*8+j] (R6-validated)
            Bf[ks][p] = *(const frag8*)(wb + p * (NE * D) + (c * 2 + ks) * 32);
}

union Pk { u32 d[4]; frag8 f; };

__device__ __forceinline__ void computeChunk(const float* __restrict__ buf,
                                             const frag8 Bf[2][3],
                                             int rtok, int xsw, int cbb,
                                             f32x4& acc) {
    const float* arow = buf + rtok * 64;
    #pragma unroll
    for (int ks = 0; ks < 2; ++ks) {
        const int c0 = (cbb + ks * 8) ^ xsw;          // swizzled 16B blocks
        const int c1 = (cbb + ks * 8 + 1) ^ xsw;
        const float4 f0 = *(const float4*)(arow + c0 * 4);
        const float4 f1 = *(const float4*)(arow + c1 * 4);
        Pk P1, P2, P3;
        split2pk(f0.x, f0.y, P1.d[0], P2.d[0], P3.d[0]);
        split2pk(f0.z, f0.w, P1.d[1], P2.d[1], P3.d[1]);
        split2pk(f1.x, f1.y, P1.d[2], P2.d[2], P3.d[2]);
        split2pk(f1.z, f1.w, P1.d[3], P2.d[3], P3.d[3]);
        // 6 products >= 2^-16 weight, small terms first (R6-validated order)
        acc = __builtin_amdgcn_mfma_f32_16x16x32_bf16(P3.f, Bf[ks][0], acc, 0, 0, 0);
        acc = __builtin_amdgcn_mfma_f32_16x16x32_bf16(P2.f, Bf[ks][1], acc, 0, 0, 0);
        acc = __builtin_amdgcn_mfma_f32_16x16x32_bf16(P1.f, Bf[ks][2], acc, 0, 0, 0);
        acc = __builtin_amdgcn_mfma_f32_16x16x32_bf16(P2.f, Bf[ks][0], acc, 0, 0, 0);
        acc = __builtin_amdgcn_mfma_f32_16x16x32_bf16(P1.f, Bf[ks][1], acc, 0, 0, 0);
        acc = __builtin_amdgcn_mfma_f32_16x16x32_bf16(P1.f, Bf[ks][0], acc, 0, 0, 0);
    }
}

__global__ void prep_w(const float* __restrict__ W, u16* __restrict__ wsp) {
    const int i = blockIdx.x * 256 + threadIdx.x;
    if (i < NE * D) {
        u16 a, b, c;
        split3(W[i], a, b, c);
        wsp[i] = a; wsp[NE * D + i] = b; wsp[2 * NE * D + i] = c;
    }
}

__global__ __launch_bounds__(TPB, 4) void gating_mfma(
    const float* __restrict__ x,
    const float* __restrict__ bias,
    const u16* __restrict__ wsp,
    float* __restrict__ out)
{
    __shared__ __align__(16) float xls[2 * BUFF];   // 32 KB -> 4 blocks/CU
    const int tid = threadIdx.x;
    const int l   = tid & 63;
    const int wvu = __builtin_amdgcn_readfirstlane(tid >> 6);
    const long blockTok = (long)blockIdx.x * TOKS;

    // staging descriptors: LDS slot s = wvu*256 + i*64 + l holds global
    // block (row r = s>>4, cb = (s&15) ^ (r&15)) of the current chunk.
    const float* gp[4];
    #pragma unroll
    for (int i = 0; i < 4; ++i) {
        const int s  = wvu * 256 + i * 64 + l;
        const int r  = s >> 4;
        const int cb = (s & 15) ^ (r & 15);
        gp[i] = x + (blockTok + r) * D + cb * 4;
    }

    const u16* __restrict__ wb = wsp + (l & 15) * D + (l >> 4) * 8;
    const int rtok = wvu * 16 + (l & 15);   // this lane's token row (A: m)
    const int xsw  = l & 15;                // swizzle key (= rtok & 15)
    const int cbb  = (l >> 4) * 2;          // base 16B block of lane's k-slice

    frag8 BfA[2][3], BfB[2][3];
    #pragma unroll
    for (int i = 0; i < 4; ++i)             // chunk 0 in flight
        async16((float*)gp[i], &xls[wvu * 1024 + i * 256]);
    loadB(wb, 0, BfA);
    f32x4 acc = {0.f, 0.f, 0.f, 0.f};

    #pragma unroll 1
    for (int c = 0; c < NCH; c += 2) {
        __syncthreads();                     // chunk c landed in buf0
        if (true) {                          // issue c+1 AFTER barrier (m97)
            #pragma unroll
            for (int i = 0; i < 4; ++i)
                async16((float*)(gp[i] + (c + 1) * 64),
                        &xls[BUFF + wvu * 1024 + i * 256]);
            loadB(wb, c + 1, BfB);
        }
        computeChunk(xls, BfA, rtok, xsw, cbb, acc);

        __syncthreads();                     // chunk c+1 landed in buf1
        if (c + 2 < NCH) {
            #pragma unroll
            for (int i = 0; i < 4; ++i)
                async16((float*)(gp[i] + (c + 2) * 64),
                        &xls[wvu * 1024 + i * 256]);
            loadB(wb, c + 2, BfA);
        }
        computeChunk(xls + BUFF, BfB, rtok, xsw, cbb, acc);
    }

    // ---- epilogue (R6-validated): C/D col=lane&15 (expert), row=quad*4+r ----
    float* lb = (float*)xls;   // buf0 region; last compute read buf1 -> safe
    #pragma unroll
    for (int r = 0; r < 4; ++r)
        lb[(wvu * 16 + (l >> 4) * 4 + r) * LSTR + (l & 15)] = acc[r];
    __syncthreads();

    float logits[NE];
    float mx = -INFINITY;
    #pragma unroll
    for (int e = 0; e < NE; ++e) {
        logits[e] = lb[l * LSTR + e] + bias[e];
        mx = fmaxf(mx, logits[e]);
    }
    float wt[NE];
    float s = 0.0f;
    #pragma unroll
    for (int e = 0; e < NE; ++e) { wt[e] = __expf(logits[e] - mx); s += wt[e]; }
    const float inv = 1.0f / s;
    #pragma unroll
    for (int e = 0; e < NE; ++e) wt[e] *= inv;

    // top-2 (ties -> lowest index, matching lax.top_k); validated R1-R6
    float b1 = -1.0f; int i1 = 0;
    float b2 = -1.0f; int i2 = 0;
    #pragma unroll
    for (int e = 0; e < NE; ++e) {
        if (wt[e] > b1)      { b2 = b1; i2 = i1; b1 = wt[e]; i1 = e; }
        else if (wt[e] > b2) { b2 = wt[e]; i2 = e; }
    }

    float* __restrict__ out0 = out;                    // gated^T  [16][65536]
    float* __restrict__ out1 = out + (long)NE * NTOK;  // weights^T[16][65536]
    #pragma unroll
    for (int i = 0; i < 4; ++i) {                      // wave's 4-expert slice
        const int e = wvu * 4 + i;
        const float g = (e == i1) ? b1 : ((e == i2) ? b2 : 0.0f);
        out0[(long)e * NTOK + blockTok + l] = g;
        out1[(long)e * NTOK + blockTok + l] = wt[e];
    }
}

extern "C" void kernel_launch(void* const* d_in, const int* in_sizes, int n_in,
                              void* d_out, int out_size, void* d_ws, size_t ws_size,
                              hipStream_t stream) {
    const float* x = (const float*)d_in[0];
    const float* W = (const float*)d_in[1];
    const float* b = (const float*)d_in[2];
    float* out = (float*)d_out;
    u16* wsp = (u16*)d_ws;                 // 3 planes x 16384 bf16 = 96 KB

    prep_w<<<64, 256, 0, stream>>>(W, wsp);
    gating_mfma<<<NTOK / TOKS, TPB, 0, stream>>>(x, b, wsp, out);
}